// Round 14
// baseline (328.262 us; speedup 1.0000x reference)
//
#include <hip/hip_runtime.h>

#define D 128
#define NC 40

typedef __attribute__((ext_vector_type(8))) short short8v;
typedef __attribute__((ext_vector_type(4))) float f32x4;

__device__ __forceinline__ unsigned short f2bf(float f) {
    unsigned u = __float_as_uint(f);
    u += 0x7fff + ((u >> 16) & 1);          // RNE
    return (unsigned short)(u >> 16);
}
__device__ __forceinline__ float bf2f(unsigned short h) {
    return __uint_as_float(((unsigned)h) << 16);
}

__device__ __forceinline__ int load_idx(const int* ei, long long pos, int is64) {
    return is64 ? ei[pos * 2] : ei[pos];
}

// per-wave int64-vs-int32 detection: check high dwords of first 64 entries
__device__ __forceinline__ int detect64(const int* __restrict__ ei) {
    int lane = threadIdx.x & 63;
    int hi = ei[lane * 2 + 1];
    return __any(hi != 0) ? 0 : 1;
}

// ---------------- graph build ----------------

// count degrees (edge blocks) + convert all weights to hi/lo bf16 planes (extra blocks)
__global__ void count_convert_kernel(const int* __restrict__ ei, int* __restrict__ deg,
                                     int E, int EB,
                                     const float* __restrict__ W1, const float* __restrict__ Wh,
                                     const float* __restrict__ Wf,
                                     unsigned short* __restrict__ Wc1, unsigned short* __restrict__ Wch0,
                                     unsigned short* __restrict__ Wch1, unsigned short* __restrict__ Wcf) {
    if (blockIdx.x < EB) {
        int is64 = detect64(ei);
        int e = blockIdx.x * 256 + threadIdx.x;
        if (e < E) {
            int d = load_idx(ei, (long long)E + e, is64);   // dst
            atomicAdd(&deg[d], 1);
        }
    } else {
        int idx = (blockIdx.x - EB) * 256 + threadIdx.x;    // 0 .. 55295
        if (idx < 49152) {
            int which = idx >> 14;                           // 0,1,2
            int j = idx & 16383;
            int nn = j >> 7, k = j & 127;
            const float* W = (which == 0) ? W1 : (which == 1) ? Wh : Wh + 16384;
            unsigned short* o = (which == 0) ? Wc1 : (which == 1) ? Wch0 : Wch1;
            float v = W[k * 128 + nn];
            unsigned short h = f2bf(v);
            o[j] = h;
            o[16384 + j] = f2bf(v - bf2f(h));
        } else if (idx < 49152 + 6144) {
            int j = idx - 49152;
            int nn = j >> 7, k = j & 127;
            float v = (nn < NC) ? Wf[k * NC + nn] : 0.f;
            unsigned short h = f2bf(v);
            Wcf[j] = h;
            Wcf[6144 + j] = f2bf(v - bf2f(h));
        }
    }
}

// phase 1: per-block (512) sums of deg
__global__ void scan1_kernel(const int* __restrict__ deg, int* __restrict__ bsum, int m) {
    int i = blockIdx.x * 512 + threadIdx.x;
    int v = (i < m) ? deg[i] : 0;
    #pragma unroll
    for (int off = 32; off; off >>= 1) v += __shfl_down(v, off, 64);
    __shared__ int ws[8];
    if ((threadIdx.x & 63) == 0) ws[threadIdx.x >> 6] = v;
    __syncthreads();
    if (threadIdx.x == 0) {
        int s = 0;
        #pragma unroll
        for (int j = 0; j < 8; ++j) s += ws[j];
        bsum[blockIdx.x] = s;
    }
}

// phase 2: inline prefix over bsum + local scan + emit rowptr/fill/dinv
__global__ void scan3_kernel(const int* __restrict__ deg, const int* __restrict__ bsum,
                             int* __restrict__ rowptr, int* __restrict__ fill,
                             float* __restrict__ dinv, int n, int E, int nb) {
    int t = threadIdx.x;                       // 512
    int lane = t & 63, w = t >> 6;
    int pv = (t < nb && t < (int)blockIdx.x) ? bsum[t] : 0;
    int rs = pv;
    #pragma unroll
    for (int off = 32; off; off >>= 1) rs += __shfl_down(rs, off, 64);
    __shared__ int red[8];
    if (lane == 0) red[w] = rs;
    __syncthreads();
    int base = 0;
    #pragma unroll
    for (int j = 0; j < 8; ++j) base += red[j];
    __syncthreads();

    int i = blockIdx.x * 512 + t;
    int v = (i < n) ? deg[i] : 0;
    int s = v;
    #pragma unroll
    for (int off = 1; off < 64; off <<= 1) {
        int x = __shfl_up(s, off, 64);
        if (lane >= off) s += x;
    }
    __shared__ int wsum[8];
    if (lane == 63) wsum[w] = s;
    __syncthreads();
    int wbase = 0;
    #pragma unroll
    for (int j = 0; j < 8; ++j) if (j < w) wbase += wsum[j];
    int excl = base + wbase + s - v;
    if (i < n) {
        rowptr[i] = excl;
        fill[i]   = excl;
        dinv[i]   = rsqrtf((float)(v + 1));   // +1 self loop
    }
    if (i == 0) rowptr[n] = E;
}

// scatter edge -> CSR, packing {src, dinv[src]}
__global__ void scatter_kernel(const int* __restrict__ ei, int* __restrict__ fill,
                               const float* __restrict__ dinv, int2* __restrict__ col2, int E) {
    int is64 = detect64(ei);
    int e = blockIdx.x * 256 + threadIdx.x;
    if (e >= E) return;
    int s = load_idx(ei, (long long)e, is64);
    int d = load_idx(ei, (long long)E + e, is64);
    int pos = atomicAdd(&fill[d], 1);
    col2[pos] = make_int2(s, __float_as_int(dinv[s]));
}

// ---------------- fused layer with in-block work stealing ----------------
// 512 threads = 8 waves, 32-node tile. Each 32-lane HALF claims single rows
// from an LDS counter (finer tail granularity than r13's pair claims).
// W b-frags hoisted above the gather (hide L2 latency under gather).
// FINAL=1: after the 128-col transform, relu(h3) is re-staged to LDS planes
// and 6 waves run the 48-col Wf MFMA writing d_out directly — deletes the
// separate final kernel and layer-3's 25.6MB h3 write.
template<int FINAL>
__launch_bounds__(512)
__global__ void fused_steal_kernel(const float4* __restrict__ h4,
                                   const unsigned short* __restrict__ Wcvt,  // [128n][128k] hi,lo
                                   const float* __restrict__ bias,
                                   const float* __restrict__ dinv,
                                   const int* __restrict__ rowptr, const int2* __restrict__ col2,
                                   float* __restrict__ out,
                                   const unsigned short* __restrict__ Wfc,   // [48n][128k] hi,lo
                                   const float* __restrict__ bf,
                                   float* __restrict__ outF, int n) {
    __shared__ unsigned short Ah[32 * 128];    // 8KB swizzled [row][k]
    __shared__ unsigned short Al[32 * 128];    // 8KB
    __shared__ int pnodes[32];
    __shared__ int cnt;
    int t = threadIdx.x;
    int wv = t >> 6, l = t & 63;
    int hp = l >> 5, li = l & 31;              // half id, lane-in-node
    int lr = l & 15, lh = l >> 4;
    if (t == 0) cnt = 16;
    __syncthreads();

    // hoisted transform W fragments: wave wv owns 16-col strip
    const unsigned short* Whi = Wcvt;
    const unsigned short* Wlo = Wcvt + 128 * 128;
    int col = wv * 16 + lr;
    short8v bh[4], bl[4];
    #pragma unroll
    for (int ks = 0; ks < 4; ++ks) {
        bh[ks] = *(const short8v*)&Whi[col * 128 + ks * 32 + lh * 8];
        bl[ks] = *(const short8v*)&Wlo[col * 128 + ks * 32 + lh * 8];
    }

    int base = blockIdx.x * 32;
    int pr = wv * 2 + hp;                      // initial rows 0..15
    while (pr < 32) {
        int row = pr;
        int node = base + row;
        int nd = (node < n) ? node : (n - 1);
        if (li == 0) pnodes[row] = (node < n) ? node : -1;
        float dn = dinv[nd];
        size_t rowbase = (size_t)nd * 32;
        float4 hv = h4[rowbase + li];
        float4 acc;
        acc.x = hv.x * dn; acc.y = hv.y * dn; acc.z = hv.z * dn; acc.w = hv.w * dn;
        int e = rowptr[nd], e1 = rowptr[nd + 1];
        for (; e + 8 <= e1; e += 8) {
            int2 c[8];
            #pragma unroll
            for (int q = 0; q < 8; ++q) c[q] = col2[e + q];
            float4 v[8];
            #pragma unroll
            for (int q = 0; q < 8; ++q) v[q] = h4[(size_t)c[q].x * 32 + li];
            #pragma unroll
            for (int q = 0; q < 8; ++q) {
                float ds = __int_as_float(c[q].y);
                acc.x += v[q].x * ds; acc.y += v[q].y * ds;
                acc.z += v[q].z * ds; acc.w += v[q].w * ds;
            }
        }
        for (; e + 4 <= e1; e += 4) {
            int2 c[4];
            #pragma unroll
            for (int q = 0; q < 4; ++q) c[q] = col2[e + q];
            float4 v[4];
            #pragma unroll
            for (int q = 0; q < 4; ++q) v[q] = h4[(size_t)c[q].x * 32 + li];
            #pragma unroll
            for (int q = 0; q < 4; ++q) {
                float ds = __int_as_float(c[q].y);
                acc.x += v[q].x * ds; acc.y += v[q].y * ds;
                acc.z += v[q].z * ds; acc.w += v[q].w * ds;
            }
        }
        for (; e < e1; ++e) {
            int2 c = col2[e];
            float ds = __int_as_float(c.y);
            float4 v = h4[(size_t)c.x * 32 + li];
            acc.x += v.x * ds; acc.y += v.y * ds; acc.z += v.z * ds; acc.w += v.w * ds;
        }
        acc.x *= dn; acc.y *= dn; acc.z *= dn; acc.w *= dn;   // bias after transform

        // split & stage row (bijective in-row swizzle)
        ushort4 hi, lo;
        hi.x = f2bf(acc.x); lo.x = f2bf(acc.x - bf2f(hi.x));
        hi.y = f2bf(acc.y); lo.y = f2bf(acc.y - bf2f(hi.y));
        hi.z = f2bf(acc.z); lo.z = f2bf(acc.z - bf2f(hi.z));
        hi.w = f2bf(acc.w); lo.w = f2bf(acc.w - bf2f(hi.w));
        int off = (row << 8) + ((li << 3) ^ ((row & 7) << 4));
        *(ushort4*)((char*)Ah + off) = hi;
        *(ushort4*)((char*)Al + off) = lo;

        // claim next row (per 32-lane half)
        int nxt;
        if (li == 0) nxt = atomicAdd(&cnt, 1);
        nxt = __shfl(nxt, hp << 5);
        pr = nxt;
    }
    __syncthreads();

    // transform MFMA: wave wv owns 16-col strip, both 16-row tiles
    float bv = bias[col];
    f32x4 o[2];
    #pragma unroll
    for (int rt = 0; rt < 2; ++rt) {
        o[rt] = (f32x4){0.f, 0.f, 0.f, 0.f};
        #pragma unroll
        for (int ks = 0; ks < 4; ++ks) {
            int arow = rt * 16 + lr;
            int aoff = (arow << 8) + (((ks << 6) + (lh << 4)) ^ ((arow & 7) << 4));
            short8v ah = *(short8v*)((char*)Ah + aoff);
            short8v al = *(short8v*)((char*)Al + aoff);
            o[rt] = __builtin_amdgcn_mfma_f32_16x16x32_bf16(ah, bh[ks], o[rt], 0, 0, 0);
            o[rt] = __builtin_amdgcn_mfma_f32_16x16x32_bf16(ah, bl[ks], o[rt], 0, 0, 0);
            o[rt] = __builtin_amdgcn_mfma_f32_16x16x32_bf16(al, bh[ks], o[rt], 0, 0, 0);
        }
    }

    if constexpr (!FINAL) {
        #pragma unroll
        for (int rt = 0; rt < 2; ++rt) {
            #pragma unroll
            for (int r = 0; r < 4; ++r) {
                int prow = pnodes[rt * 16 + lh * 4 + r];   // D layout: row=(lane>>4)*4+r
                if (prow >= 0) out[(size_t)prow * 128 + col] = fmaxf(o[rt][r] + bv, 0.f);
            }
        }
    } else {
        // h3 = relu(o + bias); re-stage as hi/lo planes (same LDS), then 48-col Wf MFMA
        __syncthreads();   // all transform A-reads done before overwrite
        #pragma unroll
        for (int rt = 0; rt < 2; ++rt) {
            #pragma unroll
            for (int r = 0; r < 4; ++r) {
                float v = fmaxf(o[rt][r] + bv, 0.f);
                unsigned short hv = f2bf(v);
                unsigned short lv = f2bf(v - bf2f(hv));
                int row = rt * 16 + lh * 4 + r;
                int boff = (row << 8) + ((2 * col) ^ ((row & 7) << 4));
                *(unsigned short*)((char*)Ah + boff) = hv;
                *(unsigned short*)((char*)Al + boff) = lv;
            }
        }
        __syncthreads();
        if (wv < 6) {
            int rt = wv & 1, ct = wv >> 1;
            int col48 = ct * 16 + lr;
            const unsigned short* Fhi = Wfc;
            const unsigned short* Flo = Wfc + 48 * 128;
            short8v fh[4], fl[4];
            #pragma unroll
            for (int ks = 0; ks < 4; ++ks) {
                fh[ks] = *(const short8v*)&Fhi[col48 * 128 + ks * 32 + lh * 8];
                fl[ks] = *(const short8v*)&Flo[col48 * 128 + ks * 32 + lh * 8];
            }
            f32x4 of = (f32x4){0.f, 0.f, 0.f, 0.f};
            #pragma unroll
            for (int ks = 0; ks < 4; ++ks) {
                int arow = rt * 16 + lr;
                int aoff = (arow << 8) + (((ks << 6) + (lh << 4)) ^ ((arow & 7) << 4));
                short8v ah = *(short8v*)((char*)Ah + aoff);
                short8v al = *(short8v*)((char*)Al + aoff);
                of = __builtin_amdgcn_mfma_f32_16x16x32_bf16(ah, fh[ks], of, 0, 0, 0);
                of = __builtin_amdgcn_mfma_f32_16x16x32_bf16(ah, fl[ks], of, 0, 0, 0);
                of = __builtin_amdgcn_mfma_f32_16x16x32_bf16(al, fh[ks], of, 0, 0, 0);
            }
            float bfv = (col48 < NC) ? bf[col48] : 0.f;
            #pragma unroll
            for (int r = 0; r < 4; ++r) {
                int prow = pnodes[rt * 16 + lh * 4 + r];
                if (prow >= 0 && col48 < NC)
                    outF[(size_t)prow * NC + col48] = of[r] + bfv;
            }
        }
    }
}

extern "C" void kernel_launch(void* const* d_in, const int* in_sizes, int n_in,
                              void* d_out, int out_size, void* d_ws, size_t ws_size,
                              hipStream_t stream) {
    const float* x  = (const float*)d_in[0];
    const int*   ei = (const int*)d_in[1];
    const float* W1 = (const float*)d_in[2];
    const float* b1 = (const float*)d_in[3];
    const float* Wh = (const float*)d_in[4];
    const float* bh = (const float*)d_in[5];
    const float* Wf = (const float*)d_in[6];
    const float* bf = (const float*)d_in[7];
    float* out = (float*)d_out;

    int n = in_sizes[0] / D;    // 50000
    int E = in_sizes[1] / 2;    // 800000

    char* ws = (char*)d_ws;
    size_t off = 0;
    auto alloc = [&](size_t bytes) {
        void* p = ws + off;
        off = (off + bytes + 255) & ~(size_t)255;
        return p;
    };
    float* B0     = (float*)alloc((size_t)n * D * 4);
    float* B1     = (float*)alloc((size_t)n * D * 4);
    int*   deg    = (int*)alloc((size_t)n * 4);
    int*   rowptr = (int*)alloc((size_t)(n + 1) * 4);
    int*   fill   = (int*)alloc((size_t)n * 4);
    int2*  col2   = (int2*)alloc((size_t)E * 8);
    float* dinv   = (float*)alloc((size_t)n * 4);
    int*   bsum   = (int*)alloc(1024 * 4);
    unsigned short* Wc1  = (unsigned short*)alloc(2 * 128 * 128 * 2);
    unsigned short* Wch0 = (unsigned short*)alloc(2 * 128 * 128 * 2);
    unsigned short* Wch1 = (unsigned short*)alloc(2 * 128 * 128 * 2);
    unsigned short* Wcf  = (unsigned short*)alloc(2 * 48 * 128 * 2);

    int EB = (E + 255) / 256;             // edge blocks
    int CB = (49152 + 6144 + 255) / 256;  // convert blocks
    int nb = (n + 511) / 512;             // 98

    hipMemsetAsync(deg, 0, (size_t)n * 4, stream);
    count_convert_kernel<<<EB + CB, 256, 0, stream>>>(ei, deg, E, EB, W1, Wh, Wf, Wc1, Wch0, Wch1, Wcf);
    scan1_kernel<<<nb, 512, 0, stream>>>(deg, bsum, n);
    scan3_kernel<<<nb, 512, 0, stream>>>(deg, bsum, rowptr, fill, dinv, n, E, nb);
    scatter_kernel<<<EB, 256, 0, stream>>>(ei, fill, dinv, col2, E);

    int fgrid = (n + 31) / 32;            // 32-node tiles, 8 waves/block

    fused_steal_kernel<0><<<fgrid, 512, 0, stream>>>((const float4*)x, Wc1, b1, dinv, rowptr, col2,
                                                     B0, Wcf, bf, out, n);
    fused_steal_kernel<0><<<fgrid, 512, 0, stream>>>((const float4*)B0, Wch0, bh, dinv, rowptr, col2,
                                                     B1, Wcf, bf, out, n);
    fused_steal_kernel<1><<<fgrid, 512, 0, stream>>>((const float4*)B1, Wch1, bh + D, dinv, rowptr, col2,
                                                     B0, Wcf, bf, out, n);
}

// Round 15
// 313.783 us; speedup vs baseline: 1.0461x; 1.0461x over previous
//
#include <hip/hip_runtime.h>

#define D 128
#define NC 40

typedef __attribute__((ext_vector_type(8))) short short8v;
typedef __attribute__((ext_vector_type(4))) float f32x4;

__device__ __forceinline__ unsigned short f2bf(float f) {
    unsigned u = __float_as_uint(f);
    u += 0x7fff + ((u >> 16) & 1);          // RNE
    return (unsigned short)(u >> 16);
}
__device__ __forceinline__ float bf2f(unsigned short h) {
    return __uint_as_float(((unsigned)h) << 16);
}

__device__ __forceinline__ int load_idx(const int* ei, long long pos, int is64) {
    return is64 ? ei[pos * 2] : ei[pos];
}

// per-wave int64-vs-int32 detection: check high dwords of first 64 entries
__device__ __forceinline__ int detect64(const int* __restrict__ ei) {
    int lane = threadIdx.x & 63;
    int hi = ei[lane * 2 + 1];
    return __any(hi != 0) ? 0 : 1;
}

// ---------------- graph build ----------------

// count degrees (edge blocks) + convert all weights to hi/lo bf16 planes (extra blocks)
__global__ void count_convert_kernel(const int* __restrict__ ei, int* __restrict__ deg,
                                     int E, int EB,
                                     const float* __restrict__ W1, const float* __restrict__ Wh,
                                     const float* __restrict__ Wf,
                                     unsigned short* __restrict__ Wc1, unsigned short* __restrict__ Wch0,
                                     unsigned short* __restrict__ Wch1, unsigned short* __restrict__ Wcf) {
    if (blockIdx.x < EB) {
        int is64 = detect64(ei);
        int e = blockIdx.x * 256 + threadIdx.x;
        if (e < E) {
            int d = load_idx(ei, (long long)E + e, is64);   // dst
            atomicAdd(&deg[d], 1);
        }
    } else {
        int idx = (blockIdx.x - EB) * 256 + threadIdx.x;    // 0 .. 55295
        if (idx < 49152) {
            int which = idx >> 14;                           // 0,1,2
            int j = idx & 16383;
            int nn = j >> 7, k = j & 127;
            const float* W = (which == 0) ? W1 : (which == 1) ? Wh : Wh + 16384;
            unsigned short* o = (which == 0) ? Wc1 : (which == 1) ? Wch0 : Wch1;
            float v = W[k * 128 + nn];
            unsigned short h = f2bf(v);
            o[j] = h;
            o[16384 + j] = f2bf(v - bf2f(h));
        } else if (idx < 49152 + 6144) {
            int j = idx - 49152;
            int nn = j >> 7, k = j & 127;
            float v = (nn < NC) ? Wf[k * NC + nn] : 0.f;
            unsigned short h = f2bf(v);
            Wcf[j] = h;
            Wcf[6144 + j] = f2bf(v - bf2f(h));
        }
    }
}

// phase 1: per-block (512) sums of deg
__global__ void scan1_kernel(const int* __restrict__ deg, int* __restrict__ bsum, int m) {
    int i = blockIdx.x * 512 + threadIdx.x;
    int v = (i < m) ? deg[i] : 0;
    #pragma unroll
    for (int off = 32; off; off >>= 1) v += __shfl_down(v, off, 64);
    __shared__ int ws[8];
    if ((threadIdx.x & 63) == 0) ws[threadIdx.x >> 6] = v;
    __syncthreads();
    if (threadIdx.x == 0) {
        int s = 0;
        #pragma unroll
        for (int j = 0; j < 8; ++j) s += ws[j];
        bsum[blockIdx.x] = s;
    }
}

// phase 2: inline prefix over bsum + local scan + emit rowptr/fill/dinv
__global__ void scan3_kernel(const int* __restrict__ deg, const int* __restrict__ bsum,
                             int* __restrict__ rowptr, int* __restrict__ fill,
                             float* __restrict__ dinv, int n, int E, int nb) {
    int t = threadIdx.x;                       // 512
    int lane = t & 63, w = t >> 6;
    int pv = (t < nb && t < (int)blockIdx.x) ? bsum[t] : 0;
    int rs = pv;
    #pragma unroll
    for (int off = 32; off; off >>= 1) rs += __shfl_down(rs, off, 64);
    __shared__ int red[8];
    if (lane == 0) red[w] = rs;
    __syncthreads();
    int base = 0;
    #pragma unroll
    for (int j = 0; j < 8; ++j) base += red[j];
    __syncthreads();

    int i = blockIdx.x * 512 + t;
    int v = (i < n) ? deg[i] : 0;
    int s = v;
    #pragma unroll
    for (int off = 1; off < 64; off <<= 1) {
        int x = __shfl_up(s, off, 64);
        if (lane >= off) s += x;
    }
    __shared__ int wsum[8];
    if (lane == 63) wsum[w] = s;
    __syncthreads();
    int wbase = 0;
    #pragma unroll
    for (int j = 0; j < 8; ++j) if (j < w) wbase += wsum[j];
    int excl = base + wbase + s - v;
    if (i < n) {
        rowptr[i] = excl;
        fill[i]   = excl;
        dinv[i]   = rsqrtf((float)(v + 1));   // +1 self loop
    }
    if (i == 0) rowptr[n] = E;
}

// scatter edge -> CSR, packing {src, dinv[src]}
__global__ void scatter_kernel(const int* __restrict__ ei, int* __restrict__ fill,
                               const float* __restrict__ dinv, int2* __restrict__ col2, int E) {
    int is64 = detect64(ei);
    int e = blockIdx.x * 256 + threadIdx.x;
    if (e >= E) return;
    int s = load_idx(ei, (long long)e, is64);
    int d = load_idx(ei, (long long)E + e, is64);
    int pos = atomicAdd(&fill[d], 1);
    col2[pos] = make_int2(s, __float_as_int(dinv[s]));
}

// ---------------- fused layer with in-block work stealing ----------------
// 512 threads = 8 waves, 32-node tile. Each 32-lane HALF claims single rows
// from an LDS counter. W b-frags loaded AFTER the gather barrier (short live
// range — r14's hoist cost VGPR 32->60 and halved occupancy).
// FINAL=1: relu(h3) re-staged to LDS planes, 6 waves run the 48-col Wf MFMA
// writing d_out directly (deletes the separate final kernel + h3 round-trip).
template<int FINAL>
__launch_bounds__(512)
__global__ void fused_steal_kernel(const float4* __restrict__ h4,
                                   const unsigned short* __restrict__ Wcvt,  // [128n][128k] hi,lo
                                   const float* __restrict__ bias,
                                   const float* __restrict__ dinv,
                                   const int* __restrict__ rowptr, const int2* __restrict__ col2,
                                   float* __restrict__ out,
                                   const unsigned short* __restrict__ Wfc,   // [48n][128k] hi,lo
                                   const float* __restrict__ bf,
                                   float* __restrict__ outF, int n) {
    __shared__ unsigned short Ah[32 * 128];    // 8KB swizzled [row][k]
    __shared__ unsigned short Al[32 * 128];    // 8KB
    __shared__ int pnodes[32];
    __shared__ int cnt;
    int t = threadIdx.x;
    int wv = t >> 6, l = t & 63;
    int hp = l >> 5, li = l & 31;              // half id, lane-in-node
    int lr = l & 15, lh = l >> 4;
    if (t == 0) cnt = 16;
    __syncthreads();

    int base = blockIdx.x * 32;
    int pr = wv * 2 + hp;                      // initial rows 0..15
    while (pr < 32) {
        int row = pr;
        int node = base + row;
        int nd = (node < n) ? node : (n - 1);
        if (li == 0) pnodes[row] = (node < n) ? node : -1;
        float dn = dinv[nd];
        size_t rowbase = (size_t)nd * 32;
        float4 hv = h4[rowbase + li];
        float4 acc;
        acc.x = hv.x * dn; acc.y = hv.y * dn; acc.z = hv.z * dn; acc.w = hv.w * dn;
        int e = rowptr[nd], e1 = rowptr[nd + 1];
        for (; e + 8 <= e1; e += 8) {
            int2 c[8];
            #pragma unroll
            for (int q = 0; q < 8; ++q) c[q] = col2[e + q];
            float4 v[8];
            #pragma unroll
            for (int q = 0; q < 8; ++q) v[q] = h4[(size_t)c[q].x * 32 + li];
            #pragma unroll
            for (int q = 0; q < 8; ++q) {
                float ds = __int_as_float(c[q].y);
                acc.x += v[q].x * ds; acc.y += v[q].y * ds;
                acc.z += v[q].z * ds; acc.w += v[q].w * ds;
            }
        }
        for (; e + 4 <= e1; e += 4) {
            int2 c[4];
            #pragma unroll
            for (int q = 0; q < 4; ++q) c[q] = col2[e + q];
            float4 v[4];
            #pragma unroll
            for (int q = 0; q < 4; ++q) v[q] = h4[(size_t)c[q].x * 32 + li];
            #pragma unroll
            for (int q = 0; q < 4; ++q) {
                float ds = __int_as_float(c[q].y);
                acc.x += v[q].x * ds; acc.y += v[q].y * ds;
                acc.z += v[q].z * ds; acc.w += v[q].w * ds;
            }
        }
        for (; e < e1; ++e) {
            int2 c = col2[e];
            float ds = __int_as_float(c.y);
            float4 v = h4[(size_t)c.x * 32 + li];
            acc.x += v.x * ds; acc.y += v.y * ds; acc.z += v.z * ds; acc.w += v.w * ds;
        }
        acc.x *= dn; acc.y *= dn; acc.z *= dn; acc.w *= dn;   // bias after transform

        // split & stage row (bijective in-row swizzle)
        ushort4 hi, lo;
        hi.x = f2bf(acc.x); lo.x = f2bf(acc.x - bf2f(hi.x));
        hi.y = f2bf(acc.y); lo.y = f2bf(acc.y - bf2f(hi.y));
        hi.z = f2bf(acc.z); lo.z = f2bf(acc.z - bf2f(hi.z));
        hi.w = f2bf(acc.w); lo.w = f2bf(acc.w - bf2f(hi.w));
        int off = (row << 8) + ((li << 3) ^ ((row & 7) << 4));
        *(ushort4*)((char*)Ah + off) = hi;
        *(ushort4*)((char*)Al + off) = lo;

        // claim next row (per 32-lane half)
        int nxt;
        if (li == 0) nxt = atomicAdd(&cnt, 1);
        nxt = __shfl(nxt, hp << 5);
        pr = nxt;
    }
    __syncthreads();

    // transform MFMA: wave wv owns 16-col strip, both 16-row tiles
    const unsigned short* Whi = Wcvt;
    const unsigned short* Wlo = Wcvt + 128 * 128;
    int col = wv * 16 + lr;
    short8v bh[4], bl[4];
    #pragma unroll
    for (int ks = 0; ks < 4; ++ks) {
        bh[ks] = *(const short8v*)&Whi[col * 128 + ks * 32 + lh * 8];
        bl[ks] = *(const short8v*)&Wlo[col * 128 + ks * 32 + lh * 8];
    }
    float bv = bias[col];
    f32x4 o[2];
    #pragma unroll
    for (int rt = 0; rt < 2; ++rt) {
        o[rt] = (f32x4){0.f, 0.f, 0.f, 0.f};
        #pragma unroll
        for (int ks = 0; ks < 4; ++ks) {
            int arow = rt * 16 + lr;
            int aoff = (arow << 8) + (((ks << 6) + (lh << 4)) ^ ((arow & 7) << 4));
            short8v ah = *(short8v*)((char*)Ah + aoff);
            short8v al = *(short8v*)((char*)Al + aoff);
            o[rt] = __builtin_amdgcn_mfma_f32_16x16x32_bf16(ah, bh[ks], o[rt], 0, 0, 0);
            o[rt] = __builtin_amdgcn_mfma_f32_16x16x32_bf16(ah, bl[ks], o[rt], 0, 0, 0);
            o[rt] = __builtin_amdgcn_mfma_f32_16x16x32_bf16(al, bh[ks], o[rt], 0, 0, 0);
        }
    }

    if constexpr (!FINAL) {
        #pragma unroll
        for (int rt = 0; rt < 2; ++rt) {
            #pragma unroll
            for (int r = 0; r < 4; ++r) {
                int prow = pnodes[rt * 16 + lh * 4 + r];   // D layout: row=(lane>>4)*4+r
                if (prow >= 0) out[(size_t)prow * 128 + col] = fmaxf(o[rt][r] + bv, 0.f);
            }
        }
    } else {
        // h3 = relu(o + bias); re-stage as hi/lo planes (same LDS), then 48-col Wf MFMA
        __syncthreads();   // all transform A-reads done before overwrite
        #pragma unroll
        for (int rt = 0; rt < 2; ++rt) {
            #pragma unroll
            for (int r = 0; r < 4; ++r) {
                float v = fmaxf(o[rt][r] + bv, 0.f);
                unsigned short hv = f2bf(v);
                unsigned short lv = f2bf(v - bf2f(hv));
                int row = rt * 16 + lh * 4 + r;
                int boff = (row << 8) + ((2 * col) ^ ((row & 7) << 4));
                *(unsigned short*)((char*)Ah + boff) = hv;
                *(unsigned short*)((char*)Al + boff) = lv;
            }
        }
        __syncthreads();
        if (wv < 6) {
            int rt = wv & 1, ct = wv >> 1;
            int col48 = ct * 16 + lr;
            const unsigned short* Fhi = Wfc;
            const unsigned short* Flo = Wfc + 48 * 128;
            short8v fh[4], fl[4];
            #pragma unroll
            for (int ks = 0; ks < 4; ++ks) {
                fh[ks] = *(const short8v*)&Fhi[col48 * 128 + ks * 32 + lh * 8];
                fl[ks] = *(const short8v*)&Flo[col48 * 128 + ks * 32 + lh * 8];
            }
            f32x4 of = (f32x4){0.f, 0.f, 0.f, 0.f};
            #pragma unroll
            for (int ks = 0; ks < 4; ++ks) {
                int arow = rt * 16 + lr;
                int aoff = (arow << 8) + (((ks << 6) + (lh << 4)) ^ ((arow & 7) << 4));
                short8v ah = *(short8v*)((char*)Ah + aoff);
                short8v al = *(short8v*)((char*)Al + aoff);
                of = __builtin_amdgcn_mfma_f32_16x16x32_bf16(ah, fh[ks], of, 0, 0, 0);
                of = __builtin_amdgcn_mfma_f32_16x16x32_bf16(ah, fl[ks], of, 0, 0, 0);
                of = __builtin_amdgcn_mfma_f32_16x16x32_bf16(al, fh[ks], of, 0, 0, 0);
            }
            float bfv = (col48 < NC) ? bf[col48] : 0.f;
            #pragma unroll
            for (int r = 0; r < 4; ++r) {
                int prow = pnodes[rt * 16 + lh * 4 + r];
                if (prow >= 0 && col48 < NC)
                    outF[(size_t)prow * NC + col48] = of[r] + bfv;
            }
        }
    }
}

extern "C" void kernel_launch(void* const* d_in, const int* in_sizes, int n_in,
                              void* d_out, int out_size, void* d_ws, size_t ws_size,
                              hipStream_t stream) {
    const float* x  = (const float*)d_in[0];
    const int*   ei = (const int*)d_in[1];
    const float* W1 = (const float*)d_in[2];
    const float* b1 = (const float*)d_in[3];
    const float* Wh = (const float*)d_in[4];
    const float* bh = (const float*)d_in[5];
    const float* Wf = (const float*)d_in[6];
    const float* bf = (const float*)d_in[7];
    float* out = (float*)d_out;

    int n = in_sizes[0] / D;    // 50000
    int E = in_sizes[1] / 2;    // 800000

    char* ws = (char*)d_ws;
    size_t off = 0;
    auto alloc = [&](size_t bytes) {
        void* p = ws + off;
        off = (off + bytes + 255) & ~(size_t)255;
        return p;
    };
    float* B0     = (float*)alloc((size_t)n * D * 4);
    float* B1     = (float*)alloc((size_t)n * D * 4);
    int*   deg    = (int*)alloc((size_t)n * 4);
    int*   rowptr = (int*)alloc((size_t)(n + 1) * 4);
    int*   fill   = (int*)alloc((size_t)n * 4);
    int2*  col2   = (int2*)alloc((size_t)E * 8);
    float* dinv   = (float*)alloc((size_t)n * 4);
    int*   bsum   = (int*)alloc(1024 * 4);
    unsigned short* Wc1  = (unsigned short*)alloc(2 * 128 * 128 * 2);
    unsigned short* Wch0 = (unsigned short*)alloc(2 * 128 * 128 * 2);
    unsigned short* Wch1 = (unsigned short*)alloc(2 * 128 * 128 * 2);
    unsigned short* Wcf  = (unsigned short*)alloc(2 * 48 * 128 * 2);

    int EB = (E + 255) / 256;             // edge blocks
    int CB = (49152 + 6144 + 255) / 256;  // convert blocks
    int nb = (n + 511) / 512;             // 98

    hipMemsetAsync(deg, 0, (size_t)n * 4, stream);
    count_convert_kernel<<<EB + CB, 256, 0, stream>>>(ei, deg, E, EB, W1, Wh, Wf, Wc1, Wch0, Wch1, Wcf);
    scan1_kernel<<<nb, 512, 0, stream>>>(deg, bsum, n);
    scan3_kernel<<<nb, 512, 0, stream>>>(deg, bsum, rowptr, fill, dinv, n, E, nb);
    scatter_kernel<<<EB, 256, 0, stream>>>(ei, fill, dinv, col2, E);

    int fgrid = (n + 31) / 32;            // 32-node tiles, 8 waves/block

    fused_steal_kernel<0><<<fgrid, 512, 0, stream>>>((const float4*)x, Wc1, b1, dinv, rowptr, col2,
                                                     B0, Wcf, bf, out, n);
    fused_steal_kernel<0><<<fgrid, 512, 0, stream>>>((const float4*)B0, Wch0, bh, dinv, rowptr, col2,
                                                     B1, Wcf, bf, out, n);
    fused_steal_kernel<1><<<fgrid, 512, 0, stream>>>((const float4*)B1, Wch1, bh + D, dinv, rowptr, col2,
                                                     B0, Wcf, bf, out, n);
}